// Round 1
// baseline (267.043 us; speedup 1.0000x reference)
//
#include <hip/hip_runtime.h>
#include <cstdint>
#include <cstddef>

typedef __bf16 bf16_t;
typedef bf16_t bf16x8 __attribute__((ext_vector_type(8)));
typedef float f32x4 __attribute__((ext_vector_type(4)));
typedef unsigned short u16x8 __attribute__((ext_vector_type(8)));
typedef unsigned short u16x4 __attribute__((ext_vector_type(4)));

#define SEQ 4096
#define BATCH 8
#define NTOK 32768      // BATCH*SEQ
#define NQKV 1536
#define DMODEL 512
#define NBH 64          // BATCH*HEADS
#define NCHUNK 8

__device__ __forceinline__ unsigned short f2b(float f) {
    union { float f; unsigned u; } c; c.f = f;
    unsigned u = c.u;
    u += 0x7fffu + ((u >> 16) & 1u);   // round-to-nearest-even
    return (unsigned short)(u >> 16);
}
__device__ __forceinline__ float b2f(unsigned short h) {
    union { unsigned u; float f; } c; c.u = ((unsigned)h) << 16;
    return c.f;
}
__device__ __forceinline__ float feat(float v) {   // elu(v)+1
    return v > 0.f ? v + 1.f : __expf(v);
}

// ---------------- prep: fp32 -> bf16 weights ----------------
__global__ __launch_bounds__(256) void prep_kernel(const float* __restrict__ wqkv,
                                                   const float* __restrict__ wout,
                                                   unsigned short* __restrict__ wqkvB,
                                                   unsigned short* __restrict__ woutB) {
    int stride = gridDim.x * 256;
    for (int j = blockIdx.x * 256 + threadIdx.x; j < NQKV * DMODEL; j += stride)
        wqkvB[j] = f2b(wqkv[j]);
    for (int j = blockIdx.x * 256 + threadIdx.x; j < DMODEL * DMODEL; j += stride)
        woutB[j] = f2b(wout[j]);
}

// ---------------- MFMA GEMM: C = A @ B^T, B stored [N][K] row-major ----------------
// MODE 0: A = fp32 x [M][K]; epilogue: feature-map on q/k ranges, store bf16 qkvF [M][1536]
// MODE 1: A = bf16 inner [M][K]; epilogue: + bias, store fp32 out [M][512]
template <int MODE>
__global__ __launch_bounds__(256) void gemm_kernel(const void* __restrict__ Ap,
                                                   const unsigned short* __restrict__ Bp,
                                                   void* __restrict__ Cp,
                                                   const float* __restrict__ bias,
                                                   int M, int N, int K, int nColBlocks) {
    __shared__ unsigned short As_[128][64];
    __shared__ unsigned short Bs_[128][64];
    const int tid = threadIdx.x;
    const int bid = blockIdx.x;
    const int brow = bid / nColBlocks, bcol = bid % nColBlocks;
    const int rowBase = brow * 128, colBase = bcol * 128;
    const int lane = tid & 63, wv = tid >> 6;
    const int wm = wv >> 1, wn = wv & 1;
    const int lr = lane & 15, lk = lane >> 4;

    f32x4 acc[4][4] = {};

    for (int kt = 0; kt < K; kt += 64) {
        // ---- stage A tile [128][64] ----
        if (MODE == 0) {
            const float* A32 = (const float*)Ap;
            int r0 = tid >> 4, c4 = (tid & 15) * 4;
            #pragma unroll
            for (int i = 0; i < 8; ++i) {
                int r = r0 + i * 16;
                f32x4 v = *(const f32x4*)&A32[(size_t)(rowBase + r) * K + kt + c4];
                u16x4 pk = { f2b(v[0]), f2b(v[1]), f2b(v[2]), f2b(v[3]) };
                *(u16x4*)&As_[r][c4] = pk;
            }
        } else {
            const unsigned short* A16 = (const unsigned short*)Ap;
            int r0 = tid >> 3, c8 = (tid & 7) * 8;
            #pragma unroll
            for (int i = 0; i < 4; ++i) {
                int r = r0 + i * 32;
                *(u16x8*)&As_[r][c8] = *(const u16x8*)&A16[(size_t)(rowBase + r) * K + kt + c8];
            }
        }
        // ---- stage B tile [128][64] (rows = output columns) ----
        {
            int r0 = tid >> 3, c8 = (tid & 7) * 8;
            #pragma unroll
            for (int i = 0; i < 4; ++i) {
                int r = r0 + i * 32;
                *(u16x8*)&Bs_[r][c8] = *(const u16x8*)&Bp[(size_t)(colBase + r) * K + kt + c8];
            }
        }
        __syncthreads();
        #pragma unroll
        for (int kk = 0; kk < 2; ++kk) {
            bf16x8 af[4], bfr[4];
            #pragma unroll
            for (int mi = 0; mi < 4; ++mi)
                af[mi] = *(const bf16x8*)&As_[wm * 64 + mi * 16 + lr][kk * 32 + lk * 8];
            #pragma unroll
            for (int ni = 0; ni < 4; ++ni)
                bfr[ni] = *(const bf16x8*)&Bs_[wn * 64 + ni * 16 + lr][kk * 32 + lk * 8];
            #pragma unroll
            for (int mi = 0; mi < 4; ++mi)
                #pragma unroll
                for (int ni = 0; ni < 4; ++ni)
                    acc[mi][ni] = __builtin_amdgcn_mfma_f32_16x16x32_bf16(af[mi], bfr[ni], acc[mi][ni], 0, 0, 0);
        }
        __syncthreads();
    }

    // ---- epilogue: C/D layout col=lane&15, row=(lane>>4)*4+reg ----
    #pragma unroll
    for (int mi = 0; mi < 4; ++mi) {
        #pragma unroll
        for (int r = 0; r < 4; ++r) {
            int grow = rowBase + wm * 64 + mi * 16 + lk * 4 + r;
            #pragma unroll
            for (int ni = 0; ni < 4; ++ni) {
                int gcol = colBase + wn * 64 + ni * 16 + lr;
                float val = acc[mi][ni][r];
                if (MODE == 0) {
                    float f;
                    if (gcol < 512) f = feat(val * 0.125f);        // q: elu(q*scale)+1
                    else if (gcol < 1024) f = feat(val);           // k: elu(k)+1
                    else f = val;                                  // v raw
                    ((unsigned short*)Cp)[(size_t)grow * NQKV + gcol] = f2b(f);
                } else {
                    ((float*)Cp)[(size_t)grow * DMODEL + gcol] = val + bias[gcol];
                }
            }
        }
    }
}

// ---------------- context partials: ctxP[chunk][bh][d][e], kcP[chunk][bh][d] ----------------
__global__ __launch_bounds__(256) void ctx_kernel(const unsigned short* __restrict__ qkvF,
                                                  float* __restrict__ ctxP,
                                                  float* __restrict__ kcP) {
    const int bh = blockIdx.x >> 3;
    const int chunk = blockIdx.x & 7;
    const int b = bh >> 3, h = bh & 7;
    const size_t rowBase = (size_t)b * SEQ + (size_t)chunk * (SEQ / NCHUNK);
    const unsigned short* kb = qkvF + rowBase * NQKV + 512 + h * 64;
    const unsigned short* vb = qkvF + rowBase * NQKV + 1024 + h * 64;
    __shared__ unsigned short kt_[32][64];
    __shared__ unsigned short vt_[32][64];
    const int t = threadIdx.x;
    const int lr = t >> 3, lc8 = (t & 7) * 8;
    const int d0 = (t >> 4) * 4, e0 = (t & 15) * 4;
    float acc[4][4] = {};
    float kacc[4] = {};
    for (int n0 = 0; n0 < SEQ / NCHUNK; n0 += 32) {
        __syncthreads();
        *(u16x8*)&kt_[lr][lc8] = *(const u16x8*)&kb[(size_t)(n0 + lr) * NQKV + lc8];
        *(u16x8*)&vt_[lr][lc8] = *(const u16x8*)&vb[(size_t)(n0 + lr) * NQKV + lc8];
        __syncthreads();
        #pragma unroll 4
        for (int nn = 0; nn < 32; ++nn) {
            u16x4 k4 = *(const u16x4*)&kt_[nn][d0];
            u16x4 v4 = *(const u16x4*)&vt_[nn][e0];
            float kv[4], vv[4];
            #pragma unroll
            for (int i = 0; i < 4; ++i) { kv[i] = b2f(k4[i]); vv[i] = b2f(v4[i]); }
            #pragma unroll
            for (int i = 0; i < 4; ++i)
                #pragma unroll
                for (int j = 0; j < 4; ++j)
                    acc[i][j] += kv[i] * vv[j];
            if (e0 == 0) {
                #pragma unroll
                for (int i = 0; i < 4; ++i) kacc[i] += kv[i];
            }
        }
    }
    float* cp = ctxP + ((size_t)chunk * NBH + bh) * 4096;
    #pragma unroll
    for (int i = 0; i < 4; ++i)
        #pragma unroll
        for (int j = 0; j < 4; ++j)
            cp[(d0 + i) * 64 + e0 + j] = acc[i][j];
    if (e0 == 0) {
        float* kp = kcP + ((size_t)chunk * NBH + bh) * 64;
        #pragma unroll
        for (int i = 0; i < 4; ++i) kp[d0 + i] = kacc[i];
    }
}

// ---------------- attention out: inner = (q @ ctx) / (q . kc), bf16 [M][512] ----------------
__global__ __launch_bounds__(256) void attn_kernel(const unsigned short* __restrict__ qkvF,
                                                   const float* __restrict__ ctxP,
                                                   const float* __restrict__ kcP,
                                                   unsigned short* __restrict__ inner) {
    const int bh = blockIdx.x >> 6;
    const int rt = blockIdx.x & 63;
    const int b = bh >> 3, h = bh & 7;
    const size_t rowBase = (size_t)b * SEQ + (size_t)rt * 64;
    __shared__ float ctxs[64][64];
    __shared__ float kcs[64];
    __shared__ float dens[64];
    __shared__ unsigned short qt[64][64];
    const int t = threadIdx.x;
    // reduce context partials into LDS
    #pragma unroll
    for (int p = 0; p < 4; ++p) {
        f32x4 s = {0.f, 0.f, 0.f, 0.f};
        for (int c = 0; c < NCHUNK; ++c)
            s += ((const f32x4*)(ctxP + ((size_t)c * NBH + bh) * 4096))[p * 256 + t];
        ((f32x4*)&ctxs[0][0])[p * 256 + t] = s;
    }
    if (t < 64) {
        float s = 0.f;
        for (int c = 0; c < NCHUNK; ++c) s += kcP[((size_t)c * NBH + bh) * 64 + t];
        kcs[t] = s;
    }
    const unsigned short* qg = qkvF + rowBase * NQKV + h * 64;
    #pragma unroll
    for (int p = 0; p < 2; ++p) {
        int idx = p * 256 + t;
        int r = idx >> 3, c8 = (idx & 7) * 8;
        *(u16x8*)&qt[r][c8] = *(const u16x8*)&qg[(size_t)r * NQKV + c8];
    }
    __syncthreads();
    if (t < 64) {
        float s = 1e-8f;
        for (int d = 0; d < 64; ++d) s += b2f(qt[t][d]) * kcs[d];
        dens[t] = s;
    }
    __syncthreads();
    const int r0 = (t >> 4) * 4, e0 = (t & 15) * 4;
    float acc[4][4] = {};
    for (int d = 0; d < 64; ++d) {
        f32x4 c4 = *(const f32x4*)&ctxs[d][e0];
        #pragma unroll
        for (int ri = 0; ri < 4; ++ri) {
            float qv = b2f(qt[r0 + ri][d]);
            #pragma unroll
            for (int ei = 0; ei < 4; ++ei) acc[ri][ei] += qv * c4[ei];
        }
    }
    #pragma unroll
    for (int ri = 0; ri < 4; ++ri) {
        float inv = 1.f / dens[r0 + ri];
        u16x4 o = { f2b(acc[ri][0] * inv), f2b(acc[ri][1] * inv),
                    f2b(acc[ri][2] * inv), f2b(acc[ri][3] * inv) };
        *(u16x4*)&inner[(rowBase + r0 + ri) * DMODEL + h * 64 + e0] = o;
    }
}

extern "C" void kernel_launch(void* const* d_in, const int* in_sizes, int n_in,
                              void* d_out, int out_size, void* d_ws, size_t ws_size,
                              hipStream_t stream) {
    (void)in_sizes; (void)n_in; (void)out_size; (void)ws_size;
    const float* x    = (const float*)d_in[0];
    const float* wqkv = (const float*)d_in[1];
    const float* wout = (const float*)d_in[2];
    const float* bout = (const float*)d_in[3];

    char* w = (char*)d_ws;
    unsigned short* qkvF  = (unsigned short*)(w);                 // 32768*1536*2 = 100663296
    unsigned short* wqkvB = (unsigned short*)(w + 100663296);     // 1536*512*2   = 1572864
    unsigned short* woutB = (unsigned short*)(w + 102236160);     // 512*512*2    = 524288
    float*          ctxP  = (float*)(w + 102760448);              // 8*64*4096*4  = 8388608
    float*          kcP   = (float*)(w + 111149056);              // 8*64*64*4    = 131072
    unsigned short* inner = (unsigned short*)(w + 111280128);     // 32768*512*2  = 33554432
    // total ws usage: 144834560 bytes

    hipLaunchKernelGGL(prep_kernel, dim3(512), dim3(256), 0, stream, wqkv, wout, wqkvB, woutB);
    hipLaunchKernelGGL((gemm_kernel<0>), dim3(256 * 12), dim3(256), 0, stream,
                       (const void*)x, wqkvB, (void*)qkvF, (const float*)nullptr,
                       NTOK, NQKV, DMODEL, 12);
    hipLaunchKernelGGL(ctx_kernel, dim3(NBH * NCHUNK), dim3(256), 0, stream, qkvF, ctxP, kcP);
    hipLaunchKernelGGL(attn_kernel, dim3(NBH * 64), dim3(256), 0, stream, qkvF, ctxP, kcP, inner);
    hipLaunchKernelGGL((gemm_kernel<1>), dim3(256 * 4), dim3(256), 0, stream,
                       (const void*)inner, woutB, (void*)d_out, bout,
                       NTOK, DMODEL, DMODEL, 4);
}

// Round 2
// 216.553 us; speedup vs baseline: 1.2331x; 1.2331x over previous
//
#include <hip/hip_runtime.h>
#include <cstdint>
#include <cstddef>

typedef __bf16 bf16_t;
typedef bf16_t bf16x8 __attribute__((ext_vector_type(8)));
typedef float f32x4 __attribute__((ext_vector_type(4)));
typedef unsigned short u16x8 __attribute__((ext_vector_type(8)));
typedef unsigned short u16x4 __attribute__((ext_vector_type(4)));

#define SEQ 4096
#define BATCH 8
#define NTOK 32768      // BATCH*SEQ
#define NQKV 1536
#define DMODEL 512
#define NBH 64          // BATCH*HEADS
#define NCHUNK 8

__device__ __forceinline__ unsigned short f2b(float f) {
    union { float f; unsigned u; } c; c.f = f;
    unsigned u = c.u;
    u += 0x7fffu + ((u >> 16) & 1u);   // round-to-nearest-even
    return (unsigned short)(u >> 16);
}
__device__ __forceinline__ float b2f(unsigned short h) {
    union { unsigned u; float f; } c; c.u = ((unsigned)h) << 16;
    return c.f;
}
__device__ __forceinline__ float feat(float v) {   // elu(v)+1
    return v > 0.f ? v + 1.f : __expf(v);
}

// async global->LDS, 16B per lane; LDS dest is wave-uniform base + lane*16
__device__ __forceinline__ void gload16(const unsigned short* g, unsigned short* lds_base) {
    __builtin_amdgcn_global_load_lds((const __attribute__((address_space(1))) unsigned int*)g,
                                     (__attribute__((address_space(3))) unsigned int*)lds_base,
                                     16, 0, 0);
}

// ---------------- prep: fp32 -> bf16 for x and both weights ----------------
__global__ __launch_bounds__(256) void prep_kernel(const float* __restrict__ x,
                                                   const float* __restrict__ wqkv,
                                                   const float* __restrict__ wout,
                                                   unsigned short* __restrict__ xB,
                                                   unsigned short* __restrict__ wqkvB,
                                                   unsigned short* __restrict__ woutB) {
    const int stride = gridDim.x * 256;
    const int t0 = blockIdx.x * 256 + threadIdx.x;
    for (int j = t0; j < NTOK * DMODEL / 4; j += stride) {
        f32x4 v = ((const f32x4*)x)[j];
        u16x4 o = { f2b(v[0]), f2b(v[1]), f2b(v[2]), f2b(v[3]) };
        ((u16x4*)xB)[j] = o;
    }
    for (int j = t0; j < NQKV * DMODEL / 4; j += stride) {
        f32x4 v = ((const f32x4*)wqkv)[j];
        u16x4 o = { f2b(v[0]), f2b(v[1]), f2b(v[2]), f2b(v[3]) };
        ((u16x4*)wqkvB)[j] = o;
    }
    for (int j = t0; j < DMODEL * DMODEL / 4; j += stride) {
        f32x4 v = ((const f32x4*)wout)[j];
        u16x4 o = { f2b(v[0]), f2b(v[1]), f2b(v[2]), f2b(v[3]) };
        ((u16x4*)woutB)[j] = o;
    }
}

// ---------------- MFMA GEMM: C = A @ B^T, A bf16 [M][K], B bf16 [N][K] ----------------
// m97 structure: 128x128 tile, BK=64, global_load_lds w=16, T2 XOR-swizzle, T1 XCD swizzle.
// MODE 0: epilogue feature-map on q/k ranges, store bf16 qkvF [M][1536]
// MODE 1: epilogue + bias, store fp32 out [M][512]
template <int MODE>
__global__ __launch_bounds__(256) void gemm_kernel(const unsigned short* __restrict__ A,
                                                   const unsigned short* __restrict__ B,
                                                   void* __restrict__ Cp,
                                                   const float* __restrict__ bias,
                                                   int M, int N, int K, int nColBlocks) {
    __shared__ unsigned short As_[128 * 64];
    __shared__ unsigned short Bs_[128 * 64];
    const int tid = threadIdx.x;
    // bijective XCD swizzle (grid divisible by 8): each XCD gets a contiguous tile range
    const int nwg = gridDim.x;
    int bid = blockIdx.x;
    if ((nwg & 7) == 0) bid = (bid & 7) * (nwg >> 3) + (bid >> 3);
    const int brow = bid / nColBlocks, bcol = bid % nColBlocks;
    const int rowBase = brow * 128, colBase = bcol * 128;
    const int lane = tid & 63, wv = tid >> 6;
    const int wm = wv >> 1, wn = wv & 1;
    const int lr = lane & 15, lk = lane >> 4;

    // staging coords: each wave stages 8 contiguous rows per issue (1024B linear LDS)
    const int srow = (wv << 3) + (lane >> 3);   // + i*32
    const int sslot = lane & 7;
    // fragment read swizzle
    const int xorv = (lr & 7) << 4;

    f32x4 acc[4][4] = {};

    const unsigned short* Arow = A + (size_t)rowBase * K;
    const unsigned short* Brow = B + (size_t)colBase * K;

    for (int kt = 0; kt < K; kt += 64) {
        #pragma unroll
        for (int i = 0; i < 4; ++i) {
            int row = i * 32 + srow;
            int scol = ((sslot ^ (row & 7)) << 3) + kt;
            gload16(Arow + (size_t)row * K + scol, As_ + (i * 32 + (wv << 3)) * 64);
        }
        #pragma unroll
        for (int i = 0; i < 4; ++i) {
            int row = i * 32 + srow;
            int scol = ((sslot ^ (row & 7)) << 3) + kt;
            gload16(Brow + (size_t)row * K + scol, Bs_ + (i * 32 + (wv << 3)) * 64);
        }
        __syncthreads();   // compiler emits vmcnt(0) drain before barrier
        #pragma unroll
        for (int kk = 0; kk < 2; ++kk) {
            bf16x8 af[4], bfr[4];
            #pragma unroll
            for (int mi = 0; mi < 4; ++mi) {
                int row = wm * 64 + mi * 16 + lr;
                af[mi] = *(const bf16x8*)((const char*)As_ + row * 128 + ((kk * 64 + lk * 16) ^ xorv));
            }
            #pragma unroll
            for (int ni = 0; ni < 4; ++ni) {
                int row = wn * 64 + ni * 16 + lr;
                bfr[ni] = *(const bf16x8*)((const char*)Bs_ + row * 128 + ((kk * 64 + lk * 16) ^ xorv));
            }
            #pragma unroll
            for (int mi = 0; mi < 4; ++mi)
                #pragma unroll
                for (int ni = 0; ni < 4; ++ni)
                    acc[mi][ni] = __builtin_amdgcn_mfma_f32_16x16x32_bf16(af[mi], bfr[ni], acc[mi][ni], 0, 0, 0);
        }
        __syncthreads();
    }

    // ---- epilogue: C/D layout col=lane&15, row=(lane>>4)*4+reg ----
    #pragma unroll
    for (int mi = 0; mi < 4; ++mi) {
        #pragma unroll
        for (int r = 0; r < 4; ++r) {
            int grow = rowBase + wm * 64 + mi * 16 + lk * 4 + r;
            #pragma unroll
            for (int ni = 0; ni < 4; ++ni) {
                int gcol = colBase + wn * 64 + ni * 16 + lr;
                float val = acc[mi][ni][r];
                if (MODE == 0) {
                    float f;
                    if (gcol < 512) f = feat(val * 0.125f);        // q: elu(q*scale)+1
                    else if (gcol < 1024) f = feat(val);           // k: elu(k)+1
                    else f = val;                                  // v raw
                    ((unsigned short*)Cp)[(size_t)grow * NQKV + gcol] = f2b(f);
                } else {
                    ((float*)Cp)[(size_t)grow * DMODEL + gcol] = val + bias[gcol];
                }
            }
        }
    }
}

// ---------------- context partials: ctxP[chunk][bh][d][e], kcP[chunk][bh][d] ----------------
__global__ __launch_bounds__(256) void ctx_kernel(const unsigned short* __restrict__ qkvF,
                                                  float* __restrict__ ctxP,
                                                  float* __restrict__ kcP) {
    const int bh = blockIdx.x >> 3;
    const int chunk = blockIdx.x & 7;
    const int b = bh >> 3, h = bh & 7;
    const size_t rowBase = (size_t)b * SEQ + (size_t)chunk * (SEQ / NCHUNK);
    const unsigned short* kb = qkvF + rowBase * NQKV + 512 + h * 64;
    const unsigned short* vb = qkvF + rowBase * NQKV + 1024 + h * 64;
    __shared__ unsigned short kt_[32][64];
    __shared__ unsigned short vt_[32][64];
    const int t = threadIdx.x;
    const int lr = t >> 3, lc8 = (t & 7) * 8;
    const int d0 = (t >> 4) * 4, e0 = (t & 15) * 4;
    float acc[4][4] = {};
    float kacc[4] = {};
    for (int n0 = 0; n0 < SEQ / NCHUNK; n0 += 32) {
        __syncthreads();
        *(u16x8*)&kt_[lr][lc8] = *(const u16x8*)&kb[(size_t)(n0 + lr) * NQKV + lc8];
        *(u16x8*)&vt_[lr][lc8] = *(const u16x8*)&vb[(size_t)(n0 + lr) * NQKV + lc8];
        __syncthreads();
        #pragma unroll 4
        for (int nn = 0; nn < 32; ++nn) {
            u16x4 k4 = *(const u16x4*)&kt_[nn][d0];
            u16x4 v4 = *(const u16x4*)&vt_[nn][e0];
            float kv[4], vv[4];
            #pragma unroll
            for (int i = 0; i < 4; ++i) { kv[i] = b2f(k4[i]); vv[i] = b2f(v4[i]); }
            #pragma unroll
            for (int i = 0; i < 4; ++i)
                #pragma unroll
                for (int j = 0; j < 4; ++j)
                    acc[i][j] += kv[i] * vv[j];
            if (e0 == 0) {
                #pragma unroll
                for (int i = 0; i < 4; ++i) kacc[i] += kv[i];
            }
        }
    }
    float* cp = ctxP + ((size_t)chunk * NBH + bh) * 4096;
    #pragma unroll
    for (int i = 0; i < 4; ++i)
        #pragma unroll
        for (int j = 0; j < 4; ++j)
            cp[(d0 + i) * 64 + e0 + j] = acc[i][j];
    if (e0 == 0) {
        float* kp = kcP + ((size_t)chunk * NBH + bh) * 64;
        #pragma unroll
        for (int i = 0; i < 4; ++i) kp[d0 + i] = kacc[i];
    }
}

// ---------------- attention out: inner = (q @ ctx) / (q . kc), bf16 [M][512] ----------------
__global__ __launch_bounds__(256) void attn_kernel(const unsigned short* __restrict__ qkvF,
                                                   const float* __restrict__ ctxP,
                                                   const float* __restrict__ kcP,
                                                   unsigned short* __restrict__ inner) {
    const int bh = blockIdx.x >> 6;
    const int rt = blockIdx.x & 63;
    const int b = bh >> 3, h = bh & 7;
    const size_t rowBase = (size_t)b * SEQ + (size_t)rt * 64;
    __shared__ float ctxs[64][64];
    __shared__ float kcs[64];
    __shared__ float dens[64];
    __shared__ unsigned short qt[64][64];
    const int t = threadIdx.x;
    #pragma unroll
    for (int p = 0; p < 4; ++p) {
        f32x4 s = {0.f, 0.f, 0.f, 0.f};
        for (int c = 0; c < NCHUNK; ++c)
            s += ((const f32x4*)(ctxP + ((size_t)c * NBH + bh) * 4096))[p * 256 + t];
        ((f32x4*)&ctxs[0][0])[p * 256 + t] = s;
    }
    if (t < 64) {
        float s = 0.f;
        for (int c = 0; c < NCHUNK; ++c) s += kcP[((size_t)c * NBH + bh) * 64 + t];
        kcs[t] = s;
    }
    const unsigned short* qg = qkvF + rowBase * NQKV + h * 64;
    #pragma unroll
    for (int p = 0; p < 2; ++p) {
        int idx = p * 256 + t;
        int r = idx >> 3, c8 = (idx & 7) * 8;
        *(u16x8*)&qt[r][c8] = *(const u16x8*)&qg[(size_t)r * NQKV + c8];
    }
    __syncthreads();
    if (t < 64) {
        float s = 1e-8f;
        for (int d = 0; d < 64; ++d) s += b2f(qt[t][d]) * kcs[d];
        dens[t] = s;
    }
    __syncthreads();
    const int r0 = (t >> 4) * 4, e0 = (t & 15) * 4;
    float acc[4][4] = {};
    for (int d = 0; d < 64; ++d) {
        f32x4 c4 = *(const f32x4*)&ctxs[d][e0];
        #pragma unroll
        for (int ri = 0; ri < 4; ++ri) {
            float qv = b2f(qt[r0 + ri][d]);
            #pragma unroll
            for (int ei = 0; ei < 4; ++ei) acc[ri][ei] += qv * c4[ei];
        }
    }
    #pragma unroll
    for (int ri = 0; ri < 4; ++ri) {
        float inv = 1.f / dens[r0 + ri];
        u16x4 o = { f2b(acc[ri][0] * inv), f2b(acc[ri][1] * inv),
                    f2b(acc[ri][2] * inv), f2b(acc[ri][3] * inv) };
        *(u16x4*)&inner[(rowBase + r0 + ri) * DMODEL + h * 64 + e0] = o;
    }
}

extern "C" void kernel_launch(void* const* d_in, const int* in_sizes, int n_in,
                              void* d_out, int out_size, void* d_ws, size_t ws_size,
                              hipStream_t stream) {
    (void)in_sizes; (void)n_in; (void)out_size; (void)ws_size;
    const float* x    = (const float*)d_in[0];
    const float* wqkv = (const float*)d_in[1];
    const float* wout = (const float*)d_in[2];
    const float* bout = (const float*)d_in[3];

    char* w = (char*)d_ws;
    // xB aliases inner: xB dead after gemm<0>; inner written by attn_kernel later.
    unsigned short* xB    = (unsigned short*)(w);                 // 32768*512*2  = 33554432
    unsigned short* inner = (unsigned short*)(w);                 // alias
    unsigned short* qkvF  = (unsigned short*)(w + 33554432);      // 32768*1536*2 = 100663296
    unsigned short* wqkvB = (unsigned short*)(w + 134217728);     // 1536*512*2   = 1572864
    unsigned short* woutB = (unsigned short*)(w + 135790592);     // 512*512*2    = 524288
    float*          ctxP  = (float*)(w + 136314880);              // 8*64*4096*4  = 8388608
    float*          kcP   = (float*)(w + 144703488);              // 8*64*64*4    = 131072
    // total ws usage: 144834560 bytes (same as R0)

    hipLaunchKernelGGL(prep_kernel, dim3(2048), dim3(256), 0, stream,
                       x, wqkv, wout, xB, wqkvB, woutB);
    hipLaunchKernelGGL((gemm_kernel<0>), dim3(256 * 12), dim3(256), 0, stream,
                       xB, wqkvB, (void*)qkvF, (const float*)nullptr,
                       NTOK, NQKV, DMODEL, 12);
    hipLaunchKernelGGL(ctx_kernel, dim3(NBH * NCHUNK), dim3(256), 0, stream, qkvF, ctxP, kcP);
    hipLaunchKernelGGL(attn_kernel, dim3(NBH * 64), dim3(256), 0, stream, qkvF, ctxP, kcP, inner);
    hipLaunchKernelGGL((gemm_kernel<1>), dim3(256 * 4), dim3(256), 0, stream,
                       inner, woutB, (void*)d_out, bout,
                       NTOK, DMODEL, DMODEL, 4);
}